// Round 23
// baseline (59.764 us; speedup 1.0000x reference)
//
#include <hip/hip_runtime.h>

#define LSEQ 2048
#define DIN  1330
#define NB   8
#define SPLITK 7
#define KCH 192          // 6 tiles * 32; 7*192 = 1344
#define K1PAD 1344
#define NTILE 6

typedef short bf16x8 __attribute__((ext_vector_type(8)));
typedef float f32x4  __attribute__((ext_vector_type(4)));
typedef unsigned short ushort8v __attribute__((ext_vector_type(8)));

__device__ __forceinline__ float lsef(float a, float b) {
  float m = fmaxf(a, b);
  float d = fminf(a, b) - m;
  return m + log1pf(__expf(d));
}

__device__ __forceinline__ unsigned short f2bf(float f) {   // RNE
  unsigned int u = __float_as_uint(f);
  return (unsigned short)((u + 0x7FFFu + ((u >> 16) & 1u)) >> 16);
}

__device__ __forceinline__ float4 lcomp(const float4 A, const float4 B) {
  float4 C;
  C.x = lsef(A.x + B.x, A.y + B.z);
  C.y = lsef(A.x + B.y, A.y + B.w);
  C.z = lsef(A.z + B.x, A.w + B.z);
  C.w = lsef(A.z + B.y, A.w + B.w);
  return C;
}
__device__ __forceinline__ float4 mcomp(const float4 A, const float4 B) {
  float4 C;
  C.x = fmaxf(A.x + B.x, A.y + B.z);
  C.y = fmaxf(A.x + B.y, A.y + B.w);
  C.z = fmaxf(A.z + B.x, A.w + B.z);
  C.w = fmaxf(A.z + B.y, A.w + B.w);
  return C;
}
__device__ __forceinline__ float4 shfl_up4(const float4 v, int d) {
  float4 r;
  r.x = __shfl_up(v.x, d); r.y = __shfl_up(v.y, d);
  r.z = __shfl_up(v.z, d); r.w = __shfl_up(v.w, d);
  return r;
}
__device__ __forceinline__ float4 shfl_dn4(const float4 v, int d) {
  float4 r;
  r.x = __shfl_down(v.x, d); r.y = __shfl_down(v.y, d);
  r.z = __shfl_down(v.z, d); r.w = __shfl_down(v.w, d);
  return r;
}
__device__ __forceinline__ int bmcomp(int A, int B) {
  int c0 = (A >> (B & 1)) & 1;
  int c1 = (A >> ((B >> 1) & 1)) & 1;
  return c0 | (c1 << 1);
}

// async global->LDS, 16B/lane: dest = uniform base + lane*16, src per-lane.
#define GLDS(g, l) __builtin_amdgcn_global_load_lds( \
    (const __attribute__((address_space(1))) void*)(g), \
    (__attribute__((address_space(3))) void*)(l), 16, 0, 0)

// ---------------- K0: w1 fp32 [k][h] -> w1T bf16 [h][K1PAD] (zero-padded) --------
__global__ __launch_bounds__(256) void k0_wt(
    const float* __restrict__ w1, unsigned short* __restrict__ w1T) {
  const int f = (blockIdx.x * 256 + threadIdx.x) * 4;   // 42 blocks * 1024 = 43008
  const int h = f / K1PAD, k = f % K1PAD;
  ushort4 v;
  v.x = (k     < DIN) ? f2bf(w1[(long)(k)     * 32 + h]) : (unsigned short)0;
  v.y = (k + 1 < DIN) ? f2bf(w1[(long)(k + 1) * 32 + h]) : (unsigned short)0;
  v.z = (k + 2 < DIN) ? f2bf(w1[(long)(k + 2) * 32 + h]) : (unsigned short)0;
  v.w = (k + 3 < DIN) ? f2bf(w1[(long)(k + 3) * 32 + h]) : (unsigned short)0;
  *(ushort4*)(w1T + f) = v;
}

// ---------------- K1: p[s] = x[:,ks] @ w1[ks,:] -- MFMA + dbuf global_load_lds ----
// v17 (m97 structure, correctly): x staged by GLDS double-buffered -- issue tile
// t+1 (HW-queued, UNSINKABLE), one barrier, compute tile t from LDS. r16's
// identical schedule with register staging was defeated by load-sinking (VGPR=44);
// r19's GLDS had no overlap (stage-all->drain->compute). LDS layout: x slabs
// [8][64 rows][4] (linear dest, per-lane 16B src; A-reads even 8/bank = optimal);
// w chunk [32][200] bf16 staged once (pad-200 -> 2-way-free B-reads).
// 29.2 KB LDS -> 5 blocks/CU; 5 staggered blocks keep ~40KB/CU in flight.
__global__ __launch_bounds__(256) void k1_mfma(
    const float* __restrict__ x, const unsigned short* __restrict__ w1T,
    float* __restrict__ p) {
  __shared__ float xb[2][8 * 256];            // [buf][slab*256 + row*4 + j], 16 KB
  __shared__ unsigned short wb[32 * 200];     // [h][kk] pad-200, 12.8 KB

  const int tid = threadIdx.x;
  const int rb  = blockIdx.x / SPLITK;
  const int s   = blockIdx.x % SPLITK;
  const int k0  = s * KCH;
  const long row0 = (long)rb * 64;

  const int wv   = tid >> 6;
  const int lane = tid & 63;
  const int fr   = lane & 15;
  const int fg   = lane >> 4;

  // ---- stage w chunk once: 32 h x 192 kk bf16 (reg->ds_write, L2-hot) ----
  #pragma unroll
  for (int i = 0; i < 3; ++i) {
    const int idx = (i * 256 + tid) * 8;      // 0..6136, 8 elems same h (192%8==0)
    const int h  = idx / KCH;
    const int kk = idx % KCH;
    const ushort8v v = *(const ushort8v*)(w1T + (long)h * K1PAD + k0 + kk);
    *(ushort8v*)(wb + h * 200 + kk) = v;
  }

  // ---- x tile stage: tile tt -> buffer bb ----
  auto stage_x = [&](int tt, int bb) {
    const bool tail = (s == SPLITK - 1) && (tt == NTILE - 1);
    #pragma unroll
    for (int c = 0; c < 2; ++c) {
      const int sl = wv * 2 + c;              // slab 0..7
      const int gk = k0 + tt * 32 + sl * 4;   // global k of slab start
      float* ldst = &xb[bb][sl * 256];        // lane writes ldst + lane*4 floats
      if (!tail || sl < 4) {
        const float* gsrc = x + (row0 + lane) * DIN + gk;
        GLDS(gsrc, ldst);
      } else {
        // guarded path (s=6 tile5 slabs>=4): exact zeros for k>=DIN, no OOB
        const float* rp = x + (row0 + lane) * DIN;
        float4 vv;
        vv.x = (gk     < DIN) ? rp[gk]     : 0.f;
        vv.y = (gk + 1 < DIN) ? rp[gk + 1] : 0.f;
        vv.z = (gk + 2 < DIN) ? rp[gk + 2] : 0.f;
        vv.w = (gk + 3 < DIN) ? rp[gk + 3] : 0.f;
        *(float4*)(ldst + lane * 4) = vv;
      }
    }
  };

  const unsigned short* bp0 = wb + fr * 200;         // h = fr
  const unsigned short* bp1 = wb + (16 + fr) * 200;  // h = 16+fr

  f32x4 acc0 = {0.f, 0.f, 0.f, 0.f};
  f32x4 acc1 = {0.f, 0.f, 0.f, 0.f};

  stage_x(0, 0);
  __syncthreads();                            // drains GLDS + w ds_writes

  #pragma unroll 1
  for (int t = 0; t < NTILE; ++t) {
    const int bi = t & 1;
    if (t + 1 < NTILE) stage_x(t + 1, bi ^ 1);   // in flight across compute

    // A-frag: slabs 2fg, 2fg+1; row = wv*16 + fr
    const int rofs = (wv * 16 + fr) * 4;
    const float4 u = *(const float4*)(&xb[bi][(2 * fg)     * 256 + rofs]);
    const float4 v = *(const float4*)(&xb[bi][(2 * fg + 1) * 256 + rofs]);
    bf16x8 a;
    a[0] = (short)f2bf(u.x); a[1] = (short)f2bf(u.y);
    a[2] = (short)f2bf(u.z); a[3] = (short)f2bf(u.w);
    a[4] = (short)f2bf(v.x); a[5] = (short)f2bf(v.y);
    a[6] = (short)f2bf(v.z); a[7] = (short)f2bf(v.w);

    const int wofs = t * 32 + fg * 8;
    const bf16x8 b0 = *(const bf16x8*)(bp0 + wofs);
    const bf16x8 b1 = *(const bf16x8*)(bp1 + wofs);

    acc0 = __builtin_amdgcn_mfma_f32_16x16x32_bf16(a, b0, acc0, 0, 0, 0);
    acc1 = __builtin_amdgcn_mfma_f32_16x16x32_bf16(a, b1, acc1, 0, 0, 0);

    __syncthreads();   // tile t readers done (buf reuse at t+2); tile t+1 staged
  }

  // C write: col = fr / 16+fr, row = wv*16 + fg*4 + i (m89 map, r15+-verified)
  float* ps = p + (long)s * 524288 + (row0 + wv * 16 + fg * 4) * 32;
  #pragma unroll
  for (int i = 0; i < 4; ++i) {
    ps[(long)i * 32 + fr]      = acc0[i];
    ps[(long)i * 32 + 16 + fr] = acc1[i];
  }
}

// ---------------- K2: h = sum_s p[s]+b1; em = relu(conv1d(h)+cb)@w2+b2 (r22) ----
__global__ __launch_bounds__(256) void k2_conv(
    const float* __restrict__ p, const float* __restrict__ b1,
    const float* __restrict__ cw, const float* __restrict__ cb,
    const float* __restrict__ w2, const float* __restrict__ b2,
    float* __restrict__ em, int* __restrict__ counter) {
  __shared__ float4 edgeF[4][8];
  __shared__ float4 edgeL[4][8];

  if (blockIdx.x == 0 && threadIdx.x == 0) *counter = 0;

  const int t    = threadIdx.x;
  const int g    = blockIdx.x * 256 + t;
  const int row  = g >> 3;
  const int isub = g & 7;
  const int i0   = isub << 2;
  const int li   = row & (LSEQ - 1);
  const int wv   = t >> 6;
  const int lane = t & 63;

  const float4* p4 = (const float4*)p;
  const float4 bv = ((const float4*)b1)[isub];
  float4 z; z.x = z.y = z.z = z.w = 0.f;

  auto hrow = [&](int r) -> float4 {
    float4 a = p4[(long)r * 8 + isub];
    #pragma unroll
    for (int s = 1; s < SPLITK; ++s) {
      float4 v = p4[(long)s * 131072 + (long)r * 8 + isub];
      a.x += v.x; a.y += v.y; a.z += v.z; a.w += v.w;
    }
    a.x += bv.x; a.y += bv.y; a.z += bv.z; a.w += bv.w;
    return a;
  };

  const float4 hc = hrow(row);

  if (lane < 8)   edgeF[wv][isub] = hc;
  if (lane >= 56) edgeL[wv][isub] = hc;
  __syncthreads();

  float4 hm = shfl_up4(hc, 8);
  float4 hp = shfl_dn4(hc, 8);
  if (lane < 8) {
    if (wv > 0) hm = edgeL[wv - 1][isub];
    else        hm = (li > 0) ? hrow(row - 1) : z;
  }
  if (lane >= 56) {
    if (wv < 3) hp = edgeF[wv + 1][isub];
    else        hp = (li < LSEQ - 1) ? hrow(row + 1) : z;
  }
  if (li == 0)        hm = z;
  if (li == LSEQ - 1) hp = z;

  float s[16];
  #pragma unroll
  for (int o = 0; o < 16; ++o) {
    const float4* wpq = (const float4*)(cw + o * 96 + i0 * 3);
    const float4 wa = wpq[0], wb = wpq[1], wc = wpq[2];
    s[o] = hm.x * wa.x + hc.x * wa.y + hp.x * wa.z
         + hm.y * wa.w + hc.y * wb.x + hp.y * wb.y
         + hm.z * wb.z + hc.z * wb.w + hp.z * wc.x
         + hm.w * wc.y + hc.w * wc.z + hp.w * wc.w;
  }
  #pragma unroll
  for (int o = 0; o < 16; ++o) {
    s[o] += __shfl_xor(s[o], 1, 8);
    s[o] += __shfl_xor(s[o], 2, 8);
    s[o] += __shfl_xor(s[o], 4, 8);
  }
  if (isub == 0) {
    float e0 = b2[0], e1 = b2[1];
    #pragma unroll
    for (int o = 0; o < 16; ++o) {
      float rr = fmaxf(s[o] + cb[o], 0.f);
      e0 += rr * w2[o * 2];
      e1 += rr * w2[o * 2 + 1];
    }
    float2 ev; ev.x = e0; ev.y = e1;
    *(float2*)(em + (long)row * 2) = ev;
  }
}

// ---------------- K3: per-batch CRF + fused final sum (r21/r22) ----------------
__global__ __launch_bounds__(256) void k3_crf(
    const float* __restrict__ em, const int* __restrict__ tokens_length,
    const int* __restrict__ labels, const float* __restrict__ start_trans,
    const float* __restrict__ end_trans, const float* __restrict__ trans,
    float* __restrict__ llh, int* __restrict__ counter,
    float* __restrict__ out) {
  __shared__ float sem[LSEQ * 2];
  __shared__ unsigned char hist[LSEQ];
  __shared__ float4 wmat[4];
  __shared__ float wred[4];
  __shared__ int wbm[4];
  __shared__ int s_last;

  const int t = threadIdx.x;
  const int b = blockIdx.x & 7;
  const int role = blockIdx.x >> 3;
  const int len = tokens_length[b];
  const float t00 = trans[0], t01 = trans[1], t10 = trans[2], t11 = trans[3];
  const float st0 = start_trans[0], st1 = start_trans[1];
  const float en0 = end_trans[0], en1 = end_trans[1];
  const int* lab = labels + b * LSEQ;

  const int wv   = t >> 6;
  const int lane = t & 63;

  int lo = t * 8; if (lo < 1) lo = 1;
  int hi = t * 8 + 8; if (hi > len) hi = len;

  const float4 IDENT = make_float4(0.f, -1e30f, -1e30f, 0.f);

  if (role == 0) {
    const float* ge = em + (long)b * LSEQ * 2;

    float sc = 0.f;
    {
      const int base = t * 8;
      #pragma unroll
      for (int k = 0; k < 8; ++k) {
        int l = base + k;
        if (l >= 1 && l < len) {
          int lp = lab[l - 1], lc = lab[l];
          sc += trans[lp * 2 + lc] + ge[2 * l + lc];
        }
      }
    }
    #pragma unroll
    for (int d = 1; d < 64; d <<= 1) sc += __shfl_down(sc, d);

    float4 M = IDENT;
    for (int l = lo; l < hi; ++l) {
      float2 e = *(const float2*)(ge + 2 * l);
      float4 S; S.x = t00 + e.x; S.y = t01 + e.y; S.z = t10 + e.x; S.w = t11 + e.y;
      M = lcomp(M, S);
    }
    #pragma unroll
    for (int d = 1; d < 64; d <<= 1) {
      float4 Mb = shfl_dn4(M, d);
      if (lane + d < 64) M = lcomp(M, Mb);
    }
    if (lane == 0) { wmat[wv] = M; wred[wv] = sc; }
    __syncthreads();

    if (t == 0) {
      float score_part = wred[0] + wred[1] + wred[2] + wred[3];
      float4 Mt = lcomp(lcomp(wmat[0], wmat[1]), lcomp(wmat[2], wmat[3]));
      int lab0 = lab[0];
      float s0 = (lab0 ? st1 : st0) + ge[lab0];
      int labe = lab[len - 1];
      float score = score_part + s0 + (labe ? en1 : en0);
      float a00 = st0 + ge[0], a01 = st1 + ge[1];
      float af0 = lsef(a00 + Mt.x, a01 + Mt.z);
      float af1 = lsef(a00 + Mt.y, a01 + Mt.w);
      float norm = lsef(af0 + en0, af1 + en1);
      llh[b] = score - norm;
      __threadfence();
      int old = atomicAdd(counter, 1);
      if (old == NB - 1) {
        __threadfence();
        const volatile float* lv = llh;
        float ssum = 0.f;
        #pragma unroll
        for (int i = 0; i < NB; ++i) ssum += lv[i];
        out[0] = -ssum;
      }
    }
    return;
  }

  // role 1: Viterbi (shfl scan)
  {
    const float4* src4 = (const float4*)(em + (long)b * LSEQ * 2);
    float4* dst4 = (float4*)sem;
    #pragma unroll
    for (int i = t; i < LSEQ * 2 / 4; i += 256) dst4[i] = src4[i];
    #pragma unroll
    for (int l = t; l < LSEQ; l += 256) hist[l] = 2;
  }
  __syncthreads();

  float4 M = IDENT;
  for (int l = lo; l < hi; ++l) {
    float e0 = sem[2 * l], e1 = sem[2 * l + 1];
    float4 S; S.x = t00 + e0; S.y = t01 + e1; S.z = t10 + e0; S.w = t11 + e1;
    M = mcomp(M, S);
  }
  #pragma unroll
  for (int d = 1; d < 64; d <<= 1) {
    float4 Mb = shfl_up4(M, d);
    if (lane >= d) M = mcomp(Mb, M);
  }
  float4 Mprev = shfl_up4(M, 1);
  if (lane == 63) wmat[wv] = M;
  __syncthreads();

  float4 P = IDENT;
  for (int j = 0; j < wv; ++j) P = mcomp(P, wmat[j]);
  float4 E = (lane == 0) ? P : mcomp(P, Mprev);

  {
    const float v00 = st0 + sem[0], v01 = st1 + sem[1];
    float vp0 = fmaxf(v00 + E.x, v01 + E.z);
    float vp1 = fmaxf(v00 + E.y, v01 + E.w);
    for (int l = lo; l < hi; ++l) {
      float e0 = sem[2 * l], e1 = sem[2 * l + 1];
      float s00 = vp0 + t00, s10 = vp1 + t10;
      float s01 = vp0 + t01, s11 = vp1 + t11;
      hist[l] = (unsigned char)((s00 >= s10 ? 0 : 1) | ((s01 >= s11 ? 0 : 1) << 1));
      vp0 = fmaxf(s00, s10) + e0;
      vp1 = fmaxf(s01, s11) + e1;
    }
    if (hi == len && lo < hi)
      s_last = (vp0 + en0 >= vp1 + en1) ? 0 : 1;
    if (t == 0 && len == 1)
      s_last = (v00 + en0 >= v01 + en1) ? 0 : 1;
  }

  int bm = 2;
  {
    int blo = (t == 0) ? 1 : t * 8;
    int bhi = t * 8 + 8;
    int m0 = 0, m1 = 1;
    for (int l = bhi - 1; l >= blo; --l) {
      int h = hist[l];
      m0 = (h >> m0) & 1;
      m1 = (h >> m1) & 1;
    }
    bm = m0 | (m1 << 1);
  }
  #pragma unroll
  for (int d = 1; d < 64; d <<= 1) {
    int bb = __shfl_down(bm, d);
    if (lane + d < 64) bm = bmcomp(bm, bb);
  }
  if (lane == 0) wbm[wv] = bm;
  __syncthreads();

  int suf = 2;
  for (int j = 3; j > wv; --j) suf = bmcomp(wbm[j], suf);
  const int G = bmcomp(bm, suf);
  int gn = __shfl_down(G, 1);
  if (lane == 63) gn = suf;
  const int last = s_last;

  {
    int xv = (t == 255) ? last : ((gn >> last) & 1);
    int blo = (t == 0) ? 1 : t * 8;
    int bhi = t * 8 + 8;
    float* tout = out + 1 + b * LSEQ;
    for (int l = bhi - 1; l >= blo; --l) {
      xv = (hist[l] >> xv) & 1;
      int pidx = l - 1;
      tout[pidx] = (pidx < len) ? (float)xv : 0.0f;
    }
    if (t == 255) tout[LSEQ - 1] = ((LSEQ - 1) < len) ? (float)last : 0.0f;
  }
}

extern "C" void kernel_launch(void* const* d_in, const int* in_sizes, int n_in,
                              void* d_out, int out_size, void* d_ws, size_t ws_size,
                              hipStream_t stream) {
  const float* x  = (const float*)d_in[0];
  const int*   tl = (const int*)d_in[1];
  const int*   lb = (const int*)d_in[2];
  const float* w1 = (const float*)d_in[3];
  const float* b1 = (const float*)d_in[4];
  const float* cw = (const float*)d_in[5];
  const float* cb = (const float*)d_in[6];
  const float* w2 = (const float*)d_in[7];
  const float* b2 = (const float*)d_in[8];
  const float* st = (const float*)d_in[9];
  const float* en = (const float*)d_in[10];
  const float* tr = (const float*)d_in[11];
  float* out = (float*)d_out;
  float* ws  = (float*)d_ws;

  float* p   = ws;                                   // 7 * 524288 floats (14 MB)
  float* em  = ws + (long)SPLITK * 524288;           // 32768 floats
  float* llh = em + 32768;                           // 8 floats
  int*  ctr  = (int*)(llh + 8);                      // 1 int
  unsigned short* w1T = (unsigned short*)(llh + 16); // 43008 ushorts (86 KB)

  hipLaunchKernelGGL(k0_wt, dim3(42), dim3(256), 0, stream, w1, w1T);
  hipLaunchKernelGGL(k1_mfma, dim3(256 * SPLITK), dim3(256), 0, stream, x, w1T, p);
  hipLaunchKernelGGL(k2_conv, dim3(512), dim3(256), 0, stream, p, b1, cw, cb, w2, b2, em, ctr);
  hipLaunchKernelGGL(k3_crf, dim3(16), dim3(256), 0, stream, em, tl, lb, st, en, tr, llh, ctr, out);
}

// Round 24
// 58.004 us; speedup vs baseline: 1.0303x; 1.0303x over previous
//
#include <hip/hip_runtime.h>

#define LSEQ 2048
#define DIN  1330
#define NB   8
#define SPLITK 7
#define KCH 192          // 6*32; 7*192 = 1344
#define K1PAD 1344
#define NSTEP 6

typedef short bf16x8 __attribute__((ext_vector_type(8)));
typedef float f32x4  __attribute__((ext_vector_type(4)));

__device__ __forceinline__ float lsef(float a, float b) {
  float m = fmaxf(a, b);
  float d = fminf(a, b) - m;
  return m + log1pf(__expf(d));
}

__device__ __forceinline__ unsigned short f2bf(float f) {   // RNE
  unsigned int u = __float_as_uint(f);
  return (unsigned short)((u + 0x7FFFu + ((u >> 16) & 1u)) >> 16);
}

__device__ __forceinline__ float4 lcomp(const float4 A, const float4 B) {
  float4 C;
  C.x = lsef(A.x + B.x, A.y + B.z);
  C.y = lsef(A.x + B.y, A.y + B.w);
  C.z = lsef(A.z + B.x, A.w + B.z);
  C.w = lsef(A.z + B.y, A.w + B.w);
  return C;
}
__device__ __forceinline__ float4 mcomp(const float4 A, const float4 B) {
  float4 C;
  C.x = fmaxf(A.x + B.x, A.y + B.z);
  C.y = fmaxf(A.x + B.y, A.y + B.w);
  C.z = fmaxf(A.z + B.x, A.w + B.z);
  C.w = fmaxf(A.z + B.y, A.w + B.w);
  return C;
}
__device__ __forceinline__ float4 shfl_up4(const float4 v, int d) {
  float4 r;
  r.x = __shfl_up(v.x, d); r.y = __shfl_up(v.y, d);
  r.z = __shfl_up(v.z, d); r.w = __shfl_up(v.w, d);
  return r;
}
__device__ __forceinline__ float4 shfl_dn4(const float4 v, int d) {
  float4 r;
  r.x = __shfl_down(v.x, d); r.y = __shfl_down(v.y, d);
  r.z = __shfl_down(v.z, d); r.w = __shfl_down(v.w, d);
  return r;
}
__device__ __forceinline__ int bmcomp(int A, int B) {
  int c0 = (A >> (B & 1)) & 1;
  int c1 = (A >> ((B >> 1) & 1)) & 1;
  return c0 | (c1 << 1);
}

// ---------------- K0: w1 fp32 [k][h] -> w1T bf16 [h][K1PAD] (zero-padded) --------
__global__ __launch_bounds__(256) void k0_wt(
    const float* __restrict__ w1, unsigned short* __restrict__ w1T) {
  const int f = (blockIdx.x * 256 + threadIdx.x) * 4;   // 42 blocks * 1024 = 43008
  const int h = f / K1PAD, k = f % K1PAD;
  ushort4 v;
  v.x = (k     < DIN) ? f2bf(w1[(long)(k)     * 32 + h]) : (unsigned short)0;
  v.y = (k + 1 < DIN) ? f2bf(w1[(long)(k + 1) * 32 + h]) : (unsigned short)0;
  v.z = (k + 2 < DIN) ? f2bf(w1[(long)(k + 2) * 32 + h]) : (unsigned short)0;
  v.w = (k + 3 < DIN) ? f2bf(w1[(long)(k + 3) * 32 + h]) : (unsigned short)0;
  *(ushort4*)(w1T + f) = v;
}

// ---------------- K1: p[s] = x[:,ks] @ w1[ks,:] via MFMA, zero-LDS (r17) --------
__global__ __launch_bounds__(256) void k1_mfma(
    const float* __restrict__ x, const unsigned short* __restrict__ w1T,
    float* __restrict__ p) {
  const int tid  = threadIdx.x;
  const int rb   = blockIdx.x / SPLITK;
  const int s    = blockIdx.x % SPLITK;
  const int k0   = s * KCH;

  const int wv   = tid >> 6;
  const int lane = tid & 63;
  const int fr   = lane & 15;
  const int fg   = lane >> 4;

  const long row  = (long)rb * 64 + wv * 16 + fr;
  const float* ap = x + row * DIN;
  const unsigned short* bp0 = w1T + (long)fr * K1PAD;
  const unsigned short* bp1 = w1T + (long)(16 + fr) * K1PAD;

  f32x4 acc0 = {0.f, 0.f, 0.f, 0.f};
  f32x4 acc1 = {0.f, 0.f, 0.f, 0.f};

  #pragma unroll
  for (int t = 0; t < NSTEP; ++t) {
    const int ka = k0 + t * 32 + fg * 8;
    float4 u, v;
    if (ka + 7 < DIN) {
      u = *(const float4*)(ap + ka);
      v = *(const float4*)(ap + ka + 4);
    } else {
      u = make_float4(0.f, 0.f, 0.f, 0.f);
      v = make_float4(0.f, 0.f, 0.f, 0.f);
      if (ka     < DIN) u.x = ap[ka];
      if (ka + 1 < DIN) u.y = ap[ka + 1];
      if (ka + 2 < DIN) u.z = ap[ka + 2];
      if (ka + 3 < DIN) u.w = ap[ka + 3];
      if (ka + 4 < DIN) v.x = ap[ka + 4];
      if (ka + 5 < DIN) v.y = ap[ka + 5];
      if (ka + 6 < DIN) v.z = ap[ka + 6];
      if (ka + 7 < DIN) v.w = ap[ka + 7];
    }
    bf16x8 a;
    a[0] = (short)f2bf(u.x); a[1] = (short)f2bf(u.y);
    a[2] = (short)f2bf(u.z); a[3] = (short)f2bf(u.w);
    a[4] = (short)f2bf(v.x); a[5] = (short)f2bf(v.y);
    a[6] = (short)f2bf(v.z); a[7] = (short)f2bf(v.w);

    const bf16x8 b0 = *(const bf16x8*)(bp0 + ka);
    const bf16x8 b1 = *(const bf16x8*)(bp1 + ka);

    acc0 = __builtin_amdgcn_mfma_f32_16x16x32_bf16(a, b0, acc0, 0, 0, 0);
    acc1 = __builtin_amdgcn_mfma_f32_16x16x32_bf16(a, b1, acc1, 0, 0, 0);
  }

  float* ps = p + (long)s * 524288 + ((long)rb * 64 + wv * 16 + fg * 4) * 32;
  #pragma unroll
  for (int i = 0; i < 4; ++i) {
    ps[(long)i * 32 + fr]      = acc0[i];
    ps[(long)i * 32 + 16 + fr] = acc1[i];
  }
}

// ---------------- K2: h = sum_s p[s]+b1; em = relu(conv1d(h)+cb)@w2+b2 ----------
// hc computed once/row; neighbors via shfl + LDS edge exchange; global fallback
// only for the 2 block-edge rows. Also zeroes k3's arrival counter.
__global__ __launch_bounds__(256) void k2_conv(
    const float* __restrict__ p, const float* __restrict__ b1,
    const float* __restrict__ cw, const float* __restrict__ cb,
    const float* __restrict__ w2, const float* __restrict__ b2,
    float* __restrict__ em, int* __restrict__ counter) {
  __shared__ float4 edgeF[4][8];
  __shared__ float4 edgeL[4][8];

  if (blockIdx.x == 0 && threadIdx.x == 0) *counter = 0;

  const int t    = threadIdx.x;
  const int g    = blockIdx.x * 256 + t;
  const int row  = g >> 3;
  const int isub = g & 7;
  const int i0   = isub << 2;
  const int li   = row & (LSEQ - 1);
  const int wv   = t >> 6;
  const int lane = t & 63;

  const float4* p4 = (const float4*)p;
  const float4 bv = ((const float4*)b1)[isub];
  float4 z; z.x = z.y = z.z = z.w = 0.f;

  auto hrow = [&](int r) -> float4 {
    float4 a = p4[(long)r * 8 + isub];
    #pragma unroll
    for (int s = 1; s < SPLITK; ++s) {
      float4 v = p4[(long)s * 131072 + (long)r * 8 + isub];
      a.x += v.x; a.y += v.y; a.z += v.z; a.w += v.w;
    }
    a.x += bv.x; a.y += bv.y; a.z += bv.z; a.w += bv.w;
    return a;
  };

  const float4 hc = hrow(row);

  if (lane < 8)   edgeF[wv][isub] = hc;
  if (lane >= 56) edgeL[wv][isub] = hc;
  __syncthreads();

  float4 hm = shfl_up4(hc, 8);
  float4 hp = shfl_dn4(hc, 8);
  if (lane < 8) {
    if (wv > 0) hm = edgeL[wv - 1][isub];
    else        hm = (li > 0) ? hrow(row - 1) : z;
  }
  if (lane >= 56) {
    if (wv < 3) hp = edgeF[wv + 1][isub];
    else        hp = (li < LSEQ - 1) ? hrow(row + 1) : z;
  }
  if (li == 0)        hm = z;
  if (li == LSEQ - 1) hp = z;

  float s[16];
  #pragma unroll
  for (int o = 0; o < 16; ++o) {
    const float4* wpq = (const float4*)(cw + o * 96 + i0 * 3);
    const float4 wa = wpq[0], wb = wpq[1], wc = wpq[2];
    s[o] = hm.x * wa.x + hc.x * wa.y + hp.x * wa.z
         + hm.y * wa.w + hc.y * wb.x + hp.y * wb.y
         + hm.z * wb.z + hc.z * wb.w + hp.z * wc.x
         + hm.w * wc.y + hc.w * wc.z + hp.w * wc.w;
  }
  #pragma unroll
  for (int o = 0; o < 16; ++o) {
    s[o] += __shfl_xor(s[o], 1, 8);
    s[o] += __shfl_xor(s[o], 2, 8);
    s[o] += __shfl_xor(s[o], 4, 8);
  }
  if (isub == 0) {
    float e0 = b2[0], e1 = b2[1];
    #pragma unroll
    for (int o = 0; o < 16; ++o) {
      float rr = fmaxf(s[o] + cb[o], 0.f);
      e0 += rr * w2[o * 2];
      e1 += rr * w2[o * 2 + 1];
    }
    float2 ev; ev.x = e0; ev.y = e1;
    *(float2*)(em + (long)row * 2) = ev;
  }
}

// ---------------- K3: per-batch CRF + fused final sum ----------------
__global__ __launch_bounds__(256) void k3_crf(
    const float* __restrict__ em, const int* __restrict__ tokens_length,
    const int* __restrict__ labels, const float* __restrict__ start_trans,
    const float* __restrict__ end_trans, const float* __restrict__ trans,
    float* __restrict__ llh, int* __restrict__ counter,
    float* __restrict__ out) {
  __shared__ float sem[LSEQ * 2];
  __shared__ unsigned char hist[LSEQ];
  __shared__ float4 wmat[4];
  __shared__ float wred[4];
  __shared__ int wbm[4];
  __shared__ int s_last;

  const int t = threadIdx.x;
  const int b = blockIdx.x & 7;
  const int role = blockIdx.x >> 3;
  const int len = tokens_length[b];
  const float t00 = trans[0], t01 = trans[1], t10 = trans[2], t11 = trans[3];
  const float st0 = start_trans[0], st1 = start_trans[1];
  const float en0 = end_trans[0], en1 = end_trans[1];
  const int* lab = labels + b * LSEQ;

  const int wv   = t >> 6;
  const int lane = t & 63;

  int lo = t * 8; if (lo < 1) lo = 1;
  int hi = t * 8 + 8; if (hi > len) hi = len;

  const float4 IDENT = make_float4(0.f, -1e30f, -1e30f, 0.f);

  if (role == 0) {
    const float* ge = em + (long)b * LSEQ * 2;

    float sc = 0.f;
    {
      const int base = t * 8;
      #pragma unroll
      for (int k = 0; k < 8; ++k) {
        int l = base + k;
        if (l >= 1 && l < len) {
          int lp = lab[l - 1], lc = lab[l];
          sc += trans[lp * 2 + lc] + ge[2 * l + lc];
        }
      }
    }
    #pragma unroll
    for (int d = 1; d < 64; d <<= 1) sc += __shfl_down(sc, d);

    float4 M = IDENT;
    for (int l = lo; l < hi; ++l) {
      float2 e = *(const float2*)(ge + 2 * l);
      float4 S; S.x = t00 + e.x; S.y = t01 + e.y; S.z = t10 + e.x; S.w = t11 + e.y;
      M = lcomp(M, S);
    }
    #pragma unroll
    for (int d = 1; d < 64; d <<= 1) {
      float4 Mb = shfl_dn4(M, d);
      if (lane + d < 64) M = lcomp(M, Mb);
    }
    if (lane == 0) { wmat[wv] = M; wred[wv] = sc; }
    __syncthreads();

    if (t == 0) {
      float score_part = wred[0] + wred[1] + wred[2] + wred[3];
      float4 Mt = lcomp(lcomp(wmat[0], wmat[1]), lcomp(wmat[2], wmat[3]));
      int lab0 = lab[0];
      float s0 = (lab0 ? st1 : st0) + ge[lab0];
      int labe = lab[len - 1];
      float score = score_part + s0 + (labe ? en1 : en0);
      float a00 = st0 + ge[0], a01 = st1 + ge[1];
      float af0 = lsef(a00 + Mt.x, a01 + Mt.z);
      float af1 = lsef(a00 + Mt.y, a01 + Mt.w);
      float norm = lsef(af0 + en0, af1 + en1);
      llh[b] = score - norm;
      __threadfence();
      int old = atomicAdd(counter, 1);
      if (old == NB - 1) {
        __threadfence();
        const volatile float* lv = llh;
        float ssum = 0.f;
        #pragma unroll
        for (int i = 0; i < NB; ++i) ssum += lv[i];
        out[0] = -ssum;
      }
    }
    return;
  }

  // role 1: Viterbi (shfl scan)
  {
    const float4* src4 = (const float4*)(em + (long)b * LSEQ * 2);
    float4* dst4 = (float4*)sem;
    #pragma unroll
    for (int i = t; i < LSEQ * 2 / 4; i += 256) dst4[i] = src4[i];
    #pragma unroll
    for (int l = t; l < LSEQ; l += 256) hist[l] = 2;
  }
  __syncthreads();

  float4 M = IDENT;
  for (int l = lo; l < hi; ++l) {
    float e0 = sem[2 * l], e1 = sem[2 * l + 1];
    float4 S; S.x = t00 + e0; S.y = t01 + e1; S.z = t10 + e0; S.w = t11 + e1;
    M = mcomp(M, S);
  }
  #pragma unroll
  for (int d = 1; d < 64; d <<= 1) {
    float4 Mb = shfl_up4(M, d);
    if (lane >= d) M = mcomp(Mb, M);
  }
  float4 Mprev = shfl_up4(M, 1);
  if (lane == 63) wmat[wv] = M;
  __syncthreads();

  float4 P = IDENT;
  for (int j = 0; j < wv; ++j) P = mcomp(P, wmat[j]);
  float4 E = (lane == 0) ? P : mcomp(P, Mprev);

  {
    const float v00 = st0 + sem[0], v01 = st1 + sem[1];
    float vp0 = fmaxf(v00 + E.x, v01 + E.z);
    float vp1 = fmaxf(v00 + E.y, v01 + E.w);
    for (int l = lo; l < hi; ++l) {
      float e0 = sem[2 * l], e1 = sem[2 * l + 1];
      float s00 = vp0 + t00, s10 = vp1 + t10;
      float s01 = vp0 + t01, s11 = vp1 + t11;
      hist[l] = (unsigned char)((s00 >= s10 ? 0 : 1) | ((s01 >= s11 ? 0 : 1) << 1));
      vp0 = fmaxf(s00, s10) + e0;
      vp1 = fmaxf(s01, s11) + e1;
    }
    if (hi == len && lo < hi)
      s_last = (vp0 + en0 >= vp1 + en1) ? 0 : 1;
    if (t == 0 && len == 1)
      s_last = (v00 + en0 >= v01 + en1) ? 0 : 1;
  }

  int bm = 2;
  {
    int blo = (t == 0) ? 1 : t * 8;
    int bhi = t * 8 + 8;
    int m0 = 0, m1 = 1;
    for (int l = bhi - 1; l >= blo; --l) {
      int h = hist[l];
      m0 = (h >> m0) & 1;
      m1 = (h >> m1) & 1;
    }
    bm = m0 | (m1 << 1);
  }
  #pragma unroll
  for (int d = 1; d < 64; d <<= 1) {
    int bb = __shfl_down(bm, d);
    if (lane + d < 64) bm = bmcomp(bm, bb);
  }
  if (lane == 0) wbm[wv] = bm;
  __syncthreads();

  int suf = 2;
  for (int j = 3; j > wv; --j) suf = bmcomp(wbm[j], suf);
  const int G = bmcomp(bm, suf);
  int gn = __shfl_down(G, 1);
  if (lane == 63) gn = suf;
  const int last = s_last;

  {
    int xv = (t == 255) ? last : ((gn >> last) & 1);
    int blo = (t == 0) ? 1 : t * 8;
    int bhi = t * 8 + 8;
    float* tout = out + 1 + b * LSEQ;
    for (int l = bhi - 1; l >= blo; --l) {
      xv = (hist[l] >> xv) & 1;
      int pidx = l - 1;
      tout[pidx] = (pidx < len) ? (float)xv : 0.0f;
    }
    if (t == 255) tout[LSEQ - 1] = ((LSEQ - 1) < len) ? (float)last : 0.0f;
  }
}

extern "C" void kernel_launch(void* const* d_in, const int* in_sizes, int n_in,
                              void* d_out, int out_size, void* d_ws, size_t ws_size,
                              hipStream_t stream) {
  const float* x  = (const float*)d_in[0];
  const int*   tl = (const int*)d_in[1];
  const int*   lb = (const int*)d_in[2];
  const float* w1 = (const float*)d_in[3];
  const float* b1 = (const float*)d_in[4];
  const float* cw = (const float*)d_in[5];
  const float* cb = (const float*)d_in[6];
  const float* w2 = (const float*)d_in[7];
  const float* b2 = (const float*)d_in[8];
  const float* st = (const float*)d_in[9];
  const float* en = (const float*)d_in[10];
  const float* tr = (const float*)d_in[11];
  float* out = (float*)d_out;
  float* ws  = (float*)d_ws;

  float* p   = ws;                                   // 7 * 524288 floats (14 MB)
  float* em  = ws + (long)SPLITK * 524288;           // 32768 floats
  float* llh = em + 32768;                           // 8 floats
  int*  ctr  = (int*)(llh + 8);                      // 1 int
  unsigned short* w1T = (unsigned short*)(llh + 16); // 43008 ushorts (86 KB)

  hipLaunchKernelGGL(k0_wt, dim3(42), dim3(256), 0, stream, w1, w1T);
  hipLaunchKernelGGL(k1_mfma, dim3(256 * SPLITK), dim3(256), 0, stream, x, w1T, p);
  hipLaunchKernelGGL(k2_conv, dim3(512), dim3(256), 0, stream, p, b1, cw, cb, w2, b2, em, ctr);
  hipLaunchKernelGGL(k3_crf, dim3(16), dim3(256), 0, stream, em, tl, lb, st, en, tr, llh, ctr, out);
}